// Round 5
// baseline (2046.466 us; speedup 1.0000x reference)
//
#include <hip/hip_runtime.h>
#include <hip/hip_bf16.h>
#include <stdint.h>

// Problem constants (LSTM_36825049596199)
#define B_    64
#define T_    512
#define EMB_  128
#define H_    128
#define G4    512            // 4*H
#define M_    (B_ * T_)      // 32768 rows for the input-projection GEMM

typedef __attribute__((ext_vector_type(8))) short  short8;   // 8 bf16 (4 VGPRs) MFMA frag
typedef __attribute__((ext_vector_type(4))) float  floatx4;  // MFMA acc frag
typedef __attribute__((ext_vector_type(2))) float  float2v;  // packed fp32 (v_pk_fma_f32)

#define GLDS(g, l) __builtin_amdgcn_global_load_lds( \
    (__attribute__((address_space(1))) void*)(g),    \
    (__attribute__((address_space(3))) void*)(l), 16, 0, 0)

// Opaque no-op: forces x to live in VGPRs here and makes the value
// non-rematerializable (compiler can no longer sink the defining load into
// a loop). Root cause of R1-R4 plateau: VGPR_Count=84 showed the 128
// weight floats were NEVER register-resident — W_hh was re-streamed from
// L1/L2 every timestep (~256KB/step/block ≈ 2000+ cyc, the real bottleneck).
#define PINV(x) __asm__ __volatile__("" : "+v"(x))

__device__ __forceinline__ unsigned short f2bf_bits(float f) {
  __hip_bfloat16 h = __float2bfloat16(f);
  return *reinterpret_cast<unsigned short*>(&h);
}
__device__ __forceinline__ float bf_bits2f(unsigned short u) {
  unsigned int x = ((unsigned int)u) << 16;
  return __uint_as_float(x);
}
__device__ __forceinline__ float sigm(float x) {
  return __fdividef(1.0f, 1.0f + __expf(-x));
}
__device__ __forceinline__ float tanh_fast(float x) {
  // tanh(x) = 1 - 2/(e^{2x}+1); saturates correctly at +-inf
  return 1.0f - __fdividef(2.0f, __expf(2.0f * x) + 1.0f);
}

// Butterfly sum across 8 contiguous lanes (8k..8k+7) — pure VALU DPP.
// Stages: xor1 (quad_perm 0xB1), xor2 (quad_perm 0x4E), then
// row_half_mirror (0x141, lane^7 within each 8) which substitutes the xor4
// stage because after the first two stages all quad members hold the quad sum.
__device__ __forceinline__ float bfly8_add(float x) {
  float y = x + __int_as_float(
      __builtin_amdgcn_mov_dpp(__float_as_int(x), 0xB1, 0xF, 0xF, true));
  y = y + __int_as_float(
      __builtin_amdgcn_mov_dpp(__float_as_int(y), 0x4E, 0xF, 0xF, true));
  return y + __int_as_float(
      __builtin_amdgcn_mov_dpp(__float_as_int(y), 0x141, 0xF, 0xF, true));
}

// xg element type templated: float (precise) if workspace allows, bf16 otherwise.
__device__ __forceinline__ void  store_xg(float* p, float v)  { *p = v; }
__device__ __forceinline__ void  store_xg(unsigned short* p, float v) { *p = f2bf_bits(v); }
__device__ __forceinline__ float load_xg(const float* p)  { return *p; }
__device__ __forceinline__ float load_xg(const unsigned short* p) { return bf_bits2f(*p); }

// ---------------------------------------------------------------------------
// Embedding gather: x0[b,t,:] = bf16(emb[X[b,t],:]).  float4 in, ushort4 out.
__global__ void k_gather(const int* __restrict__ X, const float* __restrict__ emb,
                         unsigned short* __restrict__ x0) {
  int i = blockIdx.x * 256 + threadIdx.x;       // over M_*32 float4 groups
  int row = i >> 5, c4 = i & 31;
  float4 v = ((const float4*)emb)[(size_t)X[row] * 32 + c4];
  ushort4 o;
  o.x = f2bf_bits(v.x); o.y = f2bf_bits(v.y); o.z = f2bf_bits(v.z); o.w = f2bf_bits(v.w);
  ((ushort4*)x0)[i] = o;
}

// Per-layer weight prep: w_ih -> bf16, bias_sum = b_ih + b_hh.
__global__ void k_prep(const float* __restrict__ w, const float* __restrict__ bi,
                       const float* __restrict__ bh, unsigned short* __restrict__ wb,
                       float* __restrict__ bias, int nw) {
  int i = blockIdx.x * blockDim.x + threadIdx.x;
  int stride = gridDim.x * blockDim.x;
  for (int k = i; k < nw; k += stride) wb[k] = f2bf_bits(w[k]);
  for (int k = i; k < 2 * G4; k += stride) bias[k] = bi[k] + bh[k];
}

// ---------------------------------------------------------------------------
// Input-projection GEMM (NT): xg[dir][m][n] = sum_k A[m][k]*W[dir][n][k] + bias[dir][n]
// 128x128 tile, BK=32, 256 threads. global_load_lds width-16 staging; k-chunk
// XOR swizzle so ds_read_b128 frag reads are 2-way (free).
template <typename XG_T>
__global__ __launch_bounds__(256, 2) void k_gemm(
    const unsigned short* __restrict__ A,   // [M_, K] bf16 row-major
    const unsigned short* __restrict__ W,   // [2][G4][K] bf16 row-major
    const float* __restrict__ bias,         // [2][G4]
    XG_T* __restrict__ xg,                  // [2][M_][G4]
    int K) {
  __shared__ unsigned short sA[128 * 32];
  __shared__ unsigned short sB[128 * 32];
  const int tid  = threadIdx.x;
  const int lane = tid & 63;
  const int wave = tid >> 6;
  const int mt = blockIdx.x, nt = blockIdx.y, dir = blockIdx.z;
  const size_t Arow0 = (size_t)mt * 128;
  const int    Ncol0 = nt * 128;
  const unsigned short* Wd = W + (size_t)dir * G4 * K;

  const int srow = tid >> 2;                           // LDS row (issue 0), +64 for issue 1
  const int qlog = (tid & 3) ^ ((tid >> 4) & 3);       // swizzled logical k-chunk to fetch
  auto ldsA0 = (__attribute__((address_space(3))) void*)(sA + wave * 512);
  auto ldsA1 = (__attribute__((address_space(3))) void*)(sA + 2048 + wave * 512);
  auto ldsB0 = (__attribute__((address_space(3))) void*)(sB + wave * 512);
  auto ldsB1 = (__attribute__((address_space(3))) void*)(sB + 2048 + wave * 512);

  floatx4 acc[4][4];
#pragma unroll
  for (int i = 0; i < 4; ++i)
#pragma unroll
    for (int j = 0; j < 4; ++j) acc[i][j] = (floatx4)0.0f;

  const int wrow = (wave >> 1) * 64, wcol = (wave & 1) * 64;
  const int frow = lane & 15;
  const int fq   = lane >> 4;

  for (int kt = 0; kt < K; kt += 32) {
    const unsigned short* gA0 = A  + (Arow0 + srow) * (size_t)K + kt + qlog * 8;
    const unsigned short* gB0 = Wd + (size_t)(Ncol0 + srow) * K + kt + qlog * 8;
    GLDS(gA0, ldsA0);
    GLDS(gA0 + (size_t)64 * K, ldsA1);
    GLDS(gB0, ldsB0);
    GLDS(gB0 + (size_t)64 * K, ldsB1);
    __syncthreads();   // staged data must be visible: full drain required here

    short8 af[4], bf[4];
#pragma unroll
    for (int i = 0; i < 4; ++i) {
      int r  = wrow + 16 * i + frow;
      int rn = wcol + 16 * i + frow;
      af[i] = *(const short8*)(sA + r  * 32 + ((fq ^ ((r  >> 2) & 3)) * 8));
      bf[i] = *(const short8*)(sB + rn * 32 + ((fq ^ ((rn >> 2) & 3)) * 8));
    }
#pragma unroll
    for (int i = 0; i < 4; ++i)
#pragma unroll
      for (int j = 0; j < 4; ++j)
        acc[i][j] = __builtin_amdgcn_mfma_f32_16x16x32_bf16(af[i], bf[j], acc[i][j], 0, 0, 0);
    __syncthreads();
  }

  // Epilogue: C/D layout col=lane&15, row=(lane>>4)*4+reg  [m89-verified]
  const int r0 = (lane >> 4) * 4;
  const int cc = lane & 15;
  XG_T* xgd = xg + (size_t)dir * M_ * G4;
#pragma unroll
  for (int j = 0; j < 4; ++j) {
    int gcol = Ncol0 + wcol + 16 * j + cc;
    float bs = bias[dir * G4 + gcol];
#pragma unroll
    for (int i = 0; i < 4; ++i) {
      size_t rowb = Arow0 + wrow + 16 * i + r0;
#pragma unroll
      for (int r = 0; r < 4; ++r)
        store_xg(&xgd[(rowb + r) * G4 + gcol], acc[i][j][r] + bs);
    }
  }
}

// ---------------------------------------------------------------------------
// Recurrent scan, one block per (dir,b). 1024 threads = 16 waves; wave w owns
// units u in [8w, 8w+8). Lane = (ul=lane>>3, p=lane&7); thread holds
// W_hh[g*128+u][16p .. 16p+16) for g=0..3 -> 64 fp32 weights = 32 float2
// VGPRs, PINNED (asm) so the compiler cannot re-stream them per step.
// Per step (single __syncthreads, ping-pong h in LDS):
//   4x ds_read_b128 of the lane's 16-float h slice (skew 4/16 -> 8 p-slices
//     cover all 32 banks disjointly; 8-lane same-address broadcast free)
//   32 pk_fma -> 4 gate k-partials; lanes p<4 fold xg (gate p) pre-reduction
//   3-stage DPP butterfly over the 8 p-lanes (xor1, xor2, half_mirror)
//   nonlinearities replicated over the 8 lanes; c replicated in regs
//   p==0 lanes (8/wave) write h ping-pong (1 ds_write) + y store
template <typename XG_T>
__global__ __launch_bounds__(1024, 4) void k_scan(
    const float* __restrict__ Whh,   // [2][G4][H_]
    const float* __restrict__ hx0,   // [2][B_][H_] (layer base)
    const float* __restrict__ cx0,
    const XG_T* __restrict__ xg,     // [2][M_][G4]
    unsigned short* __restrict__ y)  // [B_][T_][2*H_] bf16
{
  const int b   = blockIdx.x & 63;
  const int dir = blockIdx.x >> 6;
  const int tid = threadIdx.x;
  const int lane = tid & 63;
  const int wave = tid >> 6;
  const int p  = lane & 7;        // k-slice index (16 floats each)
  const int ul = lane >> 3;       // unit within wave (0..7)
  const int u  = wave * 8 + ul;

  // skewed h: element k stored at k + (k>>4)*4 -> the 8 p-slice bases sit at
  // dword 20p; their 4-dword groups tile all 32 banks disjointly.
  __shared__ __align__(16) float h_lds[2][160];

  // weights: w2[g][j] covers k = 16p + 2j, 2j+1
  float2v w2[4][8];
#pragma unroll
  for (int g = 0; g < 4; ++g) {
    const float* wr = Whh + ((size_t)dir * G4 + g * H_ + u) * H_ + p * 16;
#pragma unroll
    for (int q = 0; q < 4; ++q) {
      float4 v = *(const float4*)(wr + q * 4);
      w2[g][2 * q]     = float2v{v.x, v.y};
      w2[g][2 * q + 1] = float2v{v.z, v.w};
      PINV(w2[g][2 * q]);
      PINV(w2[g][2 * q + 1]);
    }
  }

  float c = cx0[(size_t)dir * B_ * H_ + b * H_ + u];   // replicated over 8 p-lanes
  if (p == 0) {
    float h0 = hx0[(size_t)dir * B_ * H_ + b * H_ + u];
    h_lds[0][u + (u >> 4) * 4] = h0;
  }
  __syncthreads();

  const XG_T* xgb = xg + ((size_t)dir * M_ + (size_t)b * T_) * G4;

  // prefetched xg for current step: lanes p<4 hold gate p, unit u
  float xv = 0.0f;
  if (p < 4) xv = load_xg(xgb + (size_t)(dir ? (T_ - 1) : 0) * G4 + p * H_ + u);

  for (int t = 0; t < T_; ++t) {
    // prefetch next step's xg (distance 1 covers L2/L3 latency)
    float xn = 0.0f;
    if (p < 4 && t + 1 < T_) {
      int ttn = dir ? (T_ - 2 - t) : (t + 1);
      xn = load_xg(xgb + (size_t)ttn * G4 + p * H_ + u);
    }

    // FMA phase: h slice k in [16p,16p+16) from skewed LDS (base dword 20p)
    const float4* h4 = (const float4*)(h_lds[t & 1] + p * 20);
    float4 hv0 = h4[0], hv1 = h4[1], hv2 = h4[2], hv3 = h4[3];
    float2v hh[8] = {
      float2v{hv0.x, hv0.y}, float2v{hv0.z, hv0.w},
      float2v{hv1.x, hv1.y}, float2v{hv1.z, hv1.w},
      float2v{hv2.x, hv2.y}, float2v{hv2.z, hv2.w},
      float2v{hv3.x, hv3.y}, float2v{hv3.z, hv3.w}};
    float2v s0 = {0, 0}, s1 = {0, 0}, s2 = {0, 0}, s3 = {0, 0};
#pragma unroll
    for (int j = 0; j < 8; ++j) {
      s0 = __builtin_elementwise_fma(w2[0][j], hh[j], s0);
      s1 = __builtin_elementwise_fma(w2[1][j], hh[j], s1);
      s2 = __builtin_elementwise_fma(w2[2][j], hh[j], s2);
      s3 = __builtin_elementwise_fma(w2[3][j], hh[j], s3);
    }
    float g0 = s0.x + s0.y, g1 = s1.x + s1.y, g2 = s2.x + s2.y, g3 = s3.x + s3.y;
    // fold xg for gate p on lanes p<4 (added exactly once across the reduction)
    g0 += (p == 0) ? xv : 0.0f;
    g1 += (p == 1) ? xv : 0.0f;
    g2 += (p == 2) ? xv : 0.0f;
    g3 += (p == 3) ? xv : 0.0f;

    // 8-lane butterfly reduction over p — DPP (VALU), no DS traffic
    g0 = bfly8_add(g0);
    g1 = bfly8_add(g1);
    g2 = bfly8_add(g2);
    g3 = bfly8_add(g3);

    // nonlinearities (replicated over the 8 p-lanes; torch gate order i,f,g,o)
    float iv = sigm(g0), fv = sigm(g1), gv = tanh_fast(g2), ov = sigm(g3);
    c = fmaf(fv, c, iv * gv);
    float h = ov * tanh_fast(c);

    if (p == 0) {
      h_lds[(t + 1) & 1][u + (u >> 4) * 4] = h;
      int tt = dir ? (T_ - 1 - t) : t;
      y[((size_t)b * T_ + tt) * (2 * H_) + dir * H_ + u] = f2bf_bits(h);
    }
    __syncthreads();   // h ping-pong visible (WAR-safe: write buf != read buf)
    xv = xn;
  }
}

// ---------------------------------------------------------------------------
// Head: out[b] = y2[b, T-1, :] . lin_w + lin_b   (64 outputs)
__global__ void k_head(const unsigned short* __restrict__ y2, const float* __restrict__ lw,
                       const float* __restrict__ lb, float* __restrict__ out) {
  int b = blockIdx.x, l = threadIdx.x;   // 64 threads = 1 wave
  const unsigned short* row = y2 + ((size_t)b * T_ + (T_ - 1)) * (2 * H_);
  float s = 0;
#pragma unroll
  for (int k = 0; k < 4; ++k) s += bf_bits2f(row[l + 64 * k]) * lw[l + 64 * k];
#pragma unroll
  for (int off = 32; off > 0; off >>= 1) s += __shfl_down(s, off);
  if (l == 0) out[b] = s + lb[0];
}

// ---------------------------------------------------------------------------
template <typename XG_T>
static inline void run_layers(const float* const* w_hh,
                              const unsigned short* x0,
                              unsigned short* y0, unsigned short* y1, unsigned short* y2,
                              const unsigned short* wb0, const unsigned short* wb1,
                              const unsigned short* wb2,
                              const float* bias0, const float* bias1, const float* bias2,
                              const float* hx, const float* cx,
                              XG_T* xg, hipStream_t stream) {
  dim3 gg(M_ / 128, G4 / 128, 2);
  k_gemm<XG_T><<<gg, 256, 0, stream>>>(x0, wb0, bias0, xg, EMB_);
  k_scan<XG_T><<<128, 1024, 0, stream>>>(w_hh[0], hx, cx, xg, y0);
  k_gemm<XG_T><<<gg, 256, 0, stream>>>(y0, wb1, bias1, xg, 2 * H_);
  k_scan<XG_T><<<128, 1024, 0, stream>>>(w_hh[1], hx + 2 * B_ * H_, cx + 2 * B_ * H_, xg, y1);
  k_gemm<XG_T><<<gg, 256, 0, stream>>>(y1, wb2, bias2, xg, 2 * H_);
  k_scan<XG_T><<<128, 1024, 0, stream>>>(w_hh[2], hx + 4 * B_ * H_, cx + 4 * B_ * H_, xg, y2);
}

extern "C" void kernel_launch(void* const* d_in, const int* in_sizes, int n_in,
                              void* d_out, int out_size, void* d_ws, size_t ws_size,
                              hipStream_t stream) {
  const int*   X   = (const int*)d_in[0];
  const float* emb = (const float*)d_in[1];
  const float* hx  = (const float*)d_in[2];
  const float* cx  = (const float*)d_in[3];
  const float* lw  = (const float*)d_in[4];
  const float* lb  = (const float*)d_in[5];
  const float* w_ih[3] = {(const float*)d_in[6],  (const float*)d_in[10], (const float*)d_in[14]};
  const float* w_hh[3] = {(const float*)d_in[7],  (const float*)d_in[11], (const float*)d_in[15]};
  const float* b_ih[3] = {(const float*)d_in[8],  (const float*)d_in[12], (const float*)d_in[16]};
  const float* b_hh[3] = {(const float*)d_in[9],  (const float*)d_in[13], (const float*)d_in[17]};
  float* out = (float*)d_out;

  char* ws = (char*)d_ws;
  size_t off = 0;
  auto carve = [&](size_t bytes) {
    char* p = ws + off;
    off = (off + bytes + 255) & ~(size_t)255;
    return p;
  };
  unsigned short* x0  = (unsigned short*)carve((size_t)M_ * EMB_ * 2);
  unsigned short* y0  = (unsigned short*)carve((size_t)M_ * 2 * H_ * 2);
  unsigned short* y1  = (unsigned short*)carve((size_t)M_ * 2 * H_ * 2);
  unsigned short* y2  = (unsigned short*)carve((size_t)M_ * 2 * H_ * 2);
  unsigned short* wb0 = (unsigned short*)carve((size_t)2 * G4 * EMB_ * 2);
  unsigned short* wb1 = (unsigned short*)carve((size_t)2 * G4 * 2 * H_ * 2);
  unsigned short* wb2 = (unsigned short*)carve((size_t)2 * G4 * 2 * H_ * 2);
  float* bias0 = (float*)carve(2 * G4 * 4);
  float* bias1 = (float*)carve(2 * G4 * 4);
  float* bias2 = (float*)carve(2 * G4 * 4);
  const size_t xg_f32_bytes = (size_t)2 * M_ * G4 * 4;
  const bool use_f32 = (off + xg_f32_bytes) <= ws_size;   // prefer fp32 xg when it fits
  void* xg = carve(use_f32 ? xg_f32_bytes : xg_f32_bytes / 2);

  k_prep<<<256, 256, 0, stream>>>(w_ih[0], b_ih[0], b_hh[0], wb0, bias0, 2 * G4 * EMB_);
  k_prep<<<256, 256, 0, stream>>>(w_ih[1], b_ih[1], b_hh[1], wb1, bias1, 2 * G4 * 2 * H_);
  k_prep<<<256, 256, 0, stream>>>(w_ih[2], b_ih[2], b_hh[2], wb2, bias2, 2 * G4 * 2 * H_);
  k_gather<<<(M_ * 32) / 256, 256, 0, stream>>>(X, emb, x0);

  if (use_f32)
    run_layers<float>(w_hh, x0, y0, y1, y2, wb0, wb1, wb2, bias0, bias1, bias2,
                      hx, cx, (float*)xg, stream);
  else
    run_layers<unsigned short>(w_hh, x0, y0, y1, y2, wb0, wb1, wb2, bias0, bias1, bias2,
                               hx, cx, (unsigned short*)xg, stream);

  k_head<<<64, 64, 0, stream>>>(y2, lw, lb, out);
}

// Round 6
// 1372.591 us; speedup vs baseline: 1.4910x; 1.4910x over previous
//
#include <hip/hip_runtime.h>
#include <hip/hip_bf16.h>
#include <stdint.h>

// Problem constants (LSTM_36825049596199)
#define B_    64
#define T_    512
#define EMB_  128
#define H_    128
#define G4    512            // 4*H
#define M_    (B_ * T_)      // 32768 rows for the input-projection GEMM

typedef __attribute__((ext_vector_type(8))) short     short8;   // 8 bf16 MFMA frag
typedef __attribute__((ext_vector_type(4))) float     floatx4;  // MFMA acc frag
typedef __attribute__((ext_vector_type(2))) _Float16  half2v;   // packed f16 (v_dot2)

#define GLDS(g, l) __builtin_amdgcn_global_load_lds( \
    (__attribute__((address_space(1))) void*)(g),    \
    (__attribute__((address_space(3))) void*)(l), 16, 0, 0)

__device__ __forceinline__ unsigned short f2bf_bits(float f) {
  __hip_bfloat16 h = __float2bfloat16(f);
  return *reinterpret_cast<unsigned short*>(&h);
}
__device__ __forceinline__ float bf_bits2f(unsigned short u) {
  unsigned int x = ((unsigned int)u) << 16;
  return __uint_as_float(x);
}
__device__ __forceinline__ float sigm(float x) {
  return __fdividef(1.0f, 1.0f + __expf(-x));
}
__device__ __forceinline__ float tanh_fast(float x) {
  return 1.0f - __fdividef(2.0f, __expf(2.0f * x) + 1.0f);
}

__device__ __forceinline__ unsigned int pack_f16x2(float a, float b) {
  half2v h; h.x = (_Float16)a; h.y = (_Float16)b;
  return __builtin_bit_cast(unsigned int, h);
}
__device__ __forceinline__ half2v u2h2(unsigned int u) {
  return __builtin_bit_cast(half2v, u);
}

#if __has_builtin(__builtin_amdgcn_fdot2)
__device__ __forceinline__ float fdot2(half2v a, half2v b, float c) {
  return __builtin_amdgcn_fdot2(a, b, c, false);   // v_dot2_f32_f16, fp32 acc
}
#else
__device__ __forceinline__ float fdot2(half2v a, half2v b, float c) {
  return fmaf((float)a.x, (float)b.x, fmaf((float)a.y, (float)b.y, c));
}
#endif

// Butterfly sum across a quad — pure VALU DPP (no DS pipe).
__device__ __forceinline__ float quad_bfly_add(float x) {
  float y = x + __int_as_float(
      __builtin_amdgcn_mov_dpp(__float_as_int(x), 0xB1, 0xF, 0xF, true));
  return y + __int_as_float(
      __builtin_amdgcn_mov_dpp(__float_as_int(y), 0x4E, 0xF, 0xF, true));
}

// xg element type templated: float (precise) if workspace allows, bf16 otherwise.
__device__ __forceinline__ void  store_xg(float* p, float v)  { *p = v; }
__device__ __forceinline__ void  store_xg(unsigned short* p, float v) { *p = f2bf_bits(v); }
__device__ __forceinline__ float load_xg(const float* p)  { return *p; }
__device__ __forceinline__ float load_xg(const unsigned short* p) { return bf_bits2f(*p); }

// ---------------------------------------------------------------------------
// Embedding gather: x0[b,t,:] = bf16(emb[X[b,t],:]).
__global__ void k_gather(const int* __restrict__ X, const float* __restrict__ emb,
                         unsigned short* __restrict__ x0) {
  int i = blockIdx.x * 256 + threadIdx.x;
  int row = i >> 5, c4 = i & 31;
  float4 v = ((const float4*)emb)[(size_t)X[row] * 32 + c4];
  ushort4 o;
  o.x = f2bf_bits(v.x); o.y = f2bf_bits(v.y); o.z = f2bf_bits(v.z); o.w = f2bf_bits(v.w);
  ((ushort4*)x0)[i] = o;
}

// Per-layer prep: w_ih -> bf16, bias_sum = b_ih + b_hh.
__global__ void k_prep(const float* __restrict__ w, const float* __restrict__ bi,
                       const float* __restrict__ bh, unsigned short* __restrict__ wb,
                       float* __restrict__ bias, int nw) {
  int i = blockIdx.x * blockDim.x + threadIdx.x;
  int stride = gridDim.x * blockDim.x;
  for (int k = i; k < nw; k += stride) wb[k] = f2bf_bits(w[k]);
  for (int k = i; k < 2 * G4; k += stride) bias[k] = bi[k] + bh[k];
}

// W_hh f16-pack into the scan's lane-coalesced layout:
// wf[((dir*16 + jq)*512 + ts)*4 + q] with d=jq*4+q, g=d>>4, jj=d&15,
// lane=ts&63, p=lane&3, u=(ts>>6)*16 + (lane>>2), k=32p+2jj.
__global__ void k_prep_whh(const float* __restrict__ Whh, unsigned int* __restrict__ wf) {
  int i = blockIdx.x * 256 + threadIdx.x;          // [0, 65536)
  int dir = i >> 15;
  int t2  = i & 0x7FFF;
  int jq  = t2 >> 11;
  int t3  = t2 & 0x7FF;
  int ts  = t3 >> 2;
  int q   = t3 & 3;
  int d   = jq * 4 + q;
  int g   = d >> 4;
  int jj  = d & 15;
  int lane = ts & 63, wave = ts >> 6;
  int p = lane & 3, ul = lane >> 2;
  int u = wave * 16 + ul;
  int k = 32 * p + 2 * jj;
  const float* wr = Whh + ((size_t)dir * G4 + g * H_ + u) * H_ + k;
  wf[i] = pack_f16x2(wr[0], wr[1]);
}

// ---------------------------------------------------------------------------
// Input-projection GEMM (NT) — unchanged from R1 (m97-style, verified).
template <typename XG_T>
__global__ __launch_bounds__(256, 2) void k_gemm(
    const unsigned short* __restrict__ A,   // [M_, K] bf16 row-major
    const unsigned short* __restrict__ W,   // [2][G4][K] bf16 row-major
    const float* __restrict__ bias,         // [2][G4]
    XG_T* __restrict__ xg,                  // [2][M_][G4]
    int K) {
  __shared__ unsigned short sA[128 * 32];
  __shared__ unsigned short sB[128 * 32];
  const int tid  = threadIdx.x;
  const int lane = tid & 63;
  const int wave = tid >> 6;
  const int mt = blockIdx.x, nt = blockIdx.y, dir = blockIdx.z;
  const size_t Arow0 = (size_t)mt * 128;
  const int    Ncol0 = nt * 128;
  const unsigned short* Wd = W + (size_t)dir * G4 * K;

  const int srow = tid >> 2;
  const int qlog = (tid & 3) ^ ((tid >> 4) & 3);
  auto ldsA0 = (__attribute__((address_space(3))) void*)(sA + wave * 512);
  auto ldsA1 = (__attribute__((address_space(3))) void*)(sA + 2048 + wave * 512);
  auto ldsB0 = (__attribute__((address_space(3))) void*)(sB + wave * 512);
  auto ldsB1 = (__attribute__((address_space(3))) void*)(sB + 2048 + wave * 512);

  floatx4 acc[4][4];
#pragma unroll
  for (int i = 0; i < 4; ++i)
#pragma unroll
    for (int j = 0; j < 4; ++j) acc[i][j] = (floatx4)0.0f;

  const int wrow = (wave >> 1) * 64, wcol = (wave & 1) * 64;
  const int frow = lane & 15;
  const int fq   = lane >> 4;

  for (int kt = 0; kt < K; kt += 32) {
    const unsigned short* gA0 = A  + (Arow0 + srow) * (size_t)K + kt + qlog * 8;
    const unsigned short* gB0 = Wd + (size_t)(Ncol0 + srow) * K + kt + qlog * 8;
    GLDS(gA0, ldsA0);
    GLDS(gA0 + (size_t)64 * K, ldsA1);
    GLDS(gB0, ldsB0);
    GLDS(gB0 + (size_t)64 * K, ldsB1);
    __syncthreads();

    short8 af[4], bf[4];
#pragma unroll
    for (int i = 0; i < 4; ++i) {
      int r  = wrow + 16 * i + frow;
      int rn = wcol + 16 * i + frow;
      af[i] = *(const short8*)(sA + r  * 32 + ((fq ^ ((r  >> 2) & 3)) * 8));
      bf[i] = *(const short8*)(sB + rn * 32 + ((fq ^ ((rn >> 2) & 3)) * 8));
    }
#pragma unroll
    for (int i = 0; i < 4; ++i)
#pragma unroll
      for (int j = 0; j < 4; ++j)
        acc[i][j] = __builtin_amdgcn_mfma_f32_16x16x32_bf16(af[i], bf[j], acc[i][j], 0, 0, 0);
    __syncthreads();
  }

  const int r0 = (lane >> 4) * 4;
  const int cc = lane & 15;
  XG_T* xgd = xg + (size_t)dir * M_ * G4;
#pragma unroll
  for (int j = 0; j < 4; ++j) {
    int gcol = Ncol0 + wcol + 16 * j + cc;
    float bs = bias[dir * G4 + gcol];
#pragma unroll
    for (int i = 0; i < 4; ++i) {
      size_t rowb = Arow0 + wrow + 16 * i + r0;
#pragma unroll
      for (int r = 0; r < 4; ++r)
        store_xg(&xgd[(rowb + r) * G4 + gcol], acc[i][j][r] + bs);
    }
  }
}

// ---------------------------------------------------------------------------
// Recurrent scan, one block per (dir,b). 512 threads = 8 waves; lane =
// (ul=lane>>2, p=lane&3); thread holds W_hh[4 gates][u][32p..32p+32) as
// 64 packed-f16 dwords (16 uint4 loads, lane-coalesced prepped layout).
// amdgpu_waves_per_eu(2,2): min=max=2 waves/EU -> 256-VGPR budget, removing
// the allocator's occupancy incentive to remat the weight loads into the
// t-loop (R1-R5 root cause: W re-streamed from L1/L2 every step, ~2000 cyc).
// Per step: 4x ds_read_b128 of packed-f16 h slice (2-way conflict = free),
// 64 v_dot2_f32_f16, DPP quad reduce, nonlins replicated, p==0 writes h+y.
template <typename XG_T>
__global__ __attribute__((amdgpu_flat_work_group_size(512, 512),
                          amdgpu_waves_per_eu(2, 2))) void k_scan(
    const unsigned int* __restrict__ wf,  // [2][16][512][4] packed f16 pairs
    const float* __restrict__ hx0,        // [2][B_][H_] (layer base)
    const float* __restrict__ cx0,
    const XG_T* __restrict__ xg,          // [2][M_][G4]
    unsigned short* __restrict__ y)       // [B_][T_][2*H_] bf16
{
  const int b   = blockIdx.x & 63;
  const int dir = blockIdx.x >> 6;
  const int tid = threadIdx.x;
  const int lane = tid & 63;
  const int wave = tid >> 6;
  const int p  = lane & 3;        // k-slice (32 k each)
  const int ul = lane >> 2;       // unit within wave
  const int u  = wave * 16 + ul;

  // h as packed f16, ping-pong. 128 ushort = 64 dwords per buffer.
  __shared__ __align__(16) unsigned short h16[2][128];

  // Weights: 16 coalesced uint4 loads; wv[i][q] is d=i*4+q, d=g*16+jj,
  // pair (k=32p+2jj, +1) of gate g. Loaded ONCE; must stay VGPR-resident.
  uint4 wv[16];
  const uint4* wfv = (const uint4*)wf;
#pragma unroll
  for (int i = 0; i < 16; ++i) wv[i] = wfv[(dir * 16 + i) * 512 + tid];

  float c = cx0[(size_t)dir * B_ * H_ + b * H_ + u];   // replicated over quad
  if (p == 0) {
    float h0 = hx0[(size_t)dir * B_ * H_ + b * H_ + u];
    h16[0][u] = (unsigned short)(pack_f16x2(h0, 0.0f) & 0xFFFF);
  }
  __syncthreads();

  const XG_T* xgb = xg + ((size_t)dir * M_ + (size_t)b * T_) * G4;

  // prefetched xg for current step: gate p, unit u (1 dword/lane)
  float xv = load_xg(xgb + (size_t)(dir ? (T_ - 1) : 0) * G4 + p * H_ + u);

  for (int t = 0; t < T_; ++t) {
    float xn = 0.0f;
    if (t + 1 < T_) {
      int ttn = dir ? (T_ - 2 - t) : (t + 1);
      xn = load_xg(xgb + (size_t)ttn * G4 + p * H_ + u);
    }

    // h slice: halves [32p,32p+32) = uint4s [4p,4p+4). Per-instr addrs are
    // 4 distinct 16B chunks; bank aliasing is 2-way (free, m136).
    const uint4* hv4 = (const uint4*)&h16[t & 1][0];
    uint4 h0v = hv4[4 * p + 0], h1v = hv4[4 * p + 1];
    uint4 h2v = hv4[4 * p + 2], h3v = hv4[4 * p + 3];
    half2v hh[16] = {
      u2h2(h0v.x), u2h2(h0v.y), u2h2(h0v.z), u2h2(h0v.w),
      u2h2(h1v.x), u2h2(h1v.y), u2h2(h1v.z), u2h2(h1v.w),
      u2h2(h2v.x), u2h2(h2v.y), u2h2(h2v.z), u2h2(h2v.w),
      u2h2(h3v.x), u2h2(h3v.y), u2h2(h3v.z), u2h2(h3v.w)};

    float g0 = 0, g1 = 0, g2 = 0, g3 = 0;
#pragma unroll
    for (int j = 0; j < 16; ++j) {
      // d = g*16 + j -> wv[d>>2][d&3]
      g0 = fdot2(u2h2(((const unsigned int*)&wv[(0 * 16 + j) >> 2])[(0 * 16 + j) & 3]), hh[j], g0);
      g1 = fdot2(u2h2(((const unsigned int*)&wv[(1 * 16 + j) >> 2])[(1 * 16 + j) & 3]), hh[j], g1);
      g2 = fdot2(u2h2(((const unsigned int*)&wv[(2 * 16 + j) >> 2])[(2 * 16 + j) & 3]), hh[j], g2);
      g3 = fdot2(u2h2(((const unsigned int*)&wv[(3 * 16 + j) >> 2])[(3 * 16 + j) & 3]), hh[j], g3);
    }
    // fold xg for gate p (added exactly once across the quad reduction)
    g0 += (p == 0) ? xv : 0.0f;
    g1 += (p == 1) ? xv : 0.0f;
    g2 += (p == 2) ? xv : 0.0f;
    g3 += (p == 3) ? xv : 0.0f;

    g0 = quad_bfly_add(g0);
    g1 = quad_bfly_add(g1);
    g2 = quad_bfly_add(g2);
    g3 = quad_bfly_add(g3);

    float iv = sigm(g0), fv = sigm(g1), gv = tanh_fast(g2), ov = sigm(g3);
    c = fmaf(fv, c, iv * gv);
    float h = ov * tanh_fast(c);

    if (p == 0) {
      h16[(t + 1) & 1][u] = (unsigned short)(pack_f16x2(h, 0.0f) & 0xFFFF);
      int tt = dir ? (T_ - 1 - t) : t;
      y[((size_t)b * T_ + tt) * (2 * H_) + dir * H_ + u] = f2bf_bits(h);
    }
    __syncthreads();
    xv = xn;
  }
}

// ---------------------------------------------------------------------------
// Head: out[b] = y2[b, T-1, :] . lin_w + lin_b
__global__ void k_head(const unsigned short* __restrict__ y2, const float* __restrict__ lw,
                       const float* __restrict__ lb, float* __restrict__ out) {
  int b = blockIdx.x, l = threadIdx.x;
  const unsigned short* row = y2 + ((size_t)b * T_ + (T_ - 1)) * (2 * H_);
  float s = 0;
#pragma unroll
  for (int k = 0; k < 4; ++k) s += bf_bits2f(row[l + 64 * k]) * lw[l + 64 * k];
#pragma unroll
  for (int off = 32; off > 0; off >>= 1) s += __shfl_down(s, off);
  if (l == 0) out[b] = s + lb[0];
}

// ---------------------------------------------------------------------------
template <typename XG_T>
static inline void run_layers(const unsigned int* const* wfs,
                              const unsigned short* x0,
                              unsigned short* y0, unsigned short* y1, unsigned short* y2,
                              const unsigned short* wb0, const unsigned short* wb1,
                              const unsigned short* wb2,
                              const float* bias0, const float* bias1, const float* bias2,
                              const float* hx, const float* cx,
                              XG_T* xg, hipStream_t stream) {
  dim3 gg(M_ / 128, G4 / 128, 2);
  k_gemm<XG_T><<<gg, 256, 0, stream>>>(x0, wb0, bias0, xg, EMB_);
  k_scan<XG_T><<<128, 512, 0, stream>>>(wfs[0], hx, cx, xg, y0);
  k_gemm<XG_T><<<gg, 256, 0, stream>>>(y0, wb1, bias1, xg, 2 * H_);
  k_scan<XG_T><<<128, 512, 0, stream>>>(wfs[1], hx + 2 * B_ * H_, cx + 2 * B_ * H_, xg, y1);
  k_gemm<XG_T><<<gg, 256, 0, stream>>>(y1, wb2, bias2, xg, 2 * H_);
  k_scan<XG_T><<<128, 512, 0, stream>>>(wfs[2], hx + 4 * B_ * H_, cx + 4 * B_ * H_, xg, y2);
}

extern "C" void kernel_launch(void* const* d_in, const int* in_sizes, int n_in,
                              void* d_out, int out_size, void* d_ws, size_t ws_size,
                              hipStream_t stream) {
  const int*   X   = (const int*)d_in[0];
  const float* emb = (const float*)d_in[1];
  const float* hx  = (const float*)d_in[2];
  const float* cx  = (const float*)d_in[3];
  const float* lw  = (const float*)d_in[4];
  const float* lb  = (const float*)d_in[5];
  const float* w_ih[3] = {(const float*)d_in[6],  (const float*)d_in[10], (const float*)d_in[14]};
  const float* w_hh[3] = {(const float*)d_in[7],  (const float*)d_in[11], (const float*)d_in[15]};
  const float* b_ih[3] = {(const float*)d_in[8],  (const float*)d_in[12], (const float*)d_in[16]};
  const float* b_hh[3] = {(const float*)d_in[9],  (const float*)d_in[13], (const float*)d_in[17]};
  float* out = (float*)d_out;

  char* ws = (char*)d_ws;
  size_t off = 0;
  auto carve = [&](size_t bytes) {
    char* p = ws + off;
    off = (off + bytes + 255) & ~(size_t)255;
    return p;
  };
  unsigned short* x0  = (unsigned short*)carve((size_t)M_ * EMB_ * 2);
  unsigned short* y0  = (unsigned short*)carve((size_t)M_ * 2 * H_ * 2);
  unsigned short* y1  = (unsigned short*)carve((size_t)M_ * 2 * H_ * 2);
  unsigned short* y2  = (unsigned short*)carve((size_t)M_ * 2 * H_ * 2);
  unsigned short* wb0 = (unsigned short*)carve((size_t)2 * G4 * EMB_ * 2);
  unsigned short* wb1 = (unsigned short*)carve((size_t)2 * G4 * 2 * H_ * 2);
  unsigned short* wb2 = (unsigned short*)carve((size_t)2 * G4 * 2 * H_ * 2);
  float* bias0 = (float*)carve(2 * G4 * 4);
  float* bias1 = (float*)carve(2 * G4 * 4);
  float* bias2 = (float*)carve(2 * G4 * 4);
  unsigned int* wf0 = (unsigned int*)carve((size_t)65536 * 4);
  unsigned int* wf1 = (unsigned int*)carve((size_t)65536 * 4);
  unsigned int* wf2 = (unsigned int*)carve((size_t)65536 * 4);
  const size_t xg_f32_bytes = (size_t)2 * M_ * G4 * 4;
  const bool use_f32 = (off + xg_f32_bytes) <= ws_size;
  void* xg = carve(use_f32 ? xg_f32_bytes : xg_f32_bytes / 2);

  k_prep<<<256, 256, 0, stream>>>(w_ih[0], b_ih[0], b_hh[0], wb0, bias0, 2 * G4 * EMB_);
  k_prep<<<256, 256, 0, stream>>>(w_ih[1], b_ih[1], b_hh[1], wb1, bias1, 2 * G4 * 2 * H_);
  k_prep<<<256, 256, 0, stream>>>(w_ih[2], b_ih[2], b_hh[2], wb2, bias2, 2 * G4 * 2 * H_);
  k_prep_whh<<<256, 256, 0, stream>>>(w_hh[0], wf0);
  k_prep_whh<<<256, 256, 0, stream>>>(w_hh[1], wf1);
  k_prep_whh<<<256, 256, 0, stream>>>(w_hh[2], wf2);
  k_gather<<<(M_ * 32) / 256, 256, 0, stream>>>(X, emb, x0);

  const unsigned int* wfs[3] = {wf0, wf1, wf2};
  if (use_f32)
    run_layers<float>(wfs, x0, y0, y1, y2, wb0, wb1, wb2, bias0, bias1, bias2,
                      hx, cx, (float*)xg, stream);
  else
    run_layers<unsigned short>(wfs, x0, y0, y1, y2, wb0, wb1, wb2, bias0, bias1, bias2,
                               hx, cx, (unsigned short*)xg, stream);

  k_head<<<64, 64, 0, stream>>>(y2, lw, lb, out);
}

// Round 7
// 1333.253 us; speedup vs baseline: 1.5349x; 1.0295x over previous
//
#include <hip/hip_runtime.h>
#include <hip/hip_bf16.h>
#include <stdint.h>

// Problem constants (LSTM_36825049596199)
#define B_    64
#define T_    512
#define EMB_  128
#define H_    128
#define G4    512            // 4*H
#define M_    (B_ * T_)      // 32768 rows for the input-projection GEMM

typedef __attribute__((ext_vector_type(8))) short     short8;   // 8 bf16 MFMA frag
typedef __attribute__((ext_vector_type(4))) float     floatx4;  // MFMA acc frag
typedef __attribute__((ext_vector_type(2))) _Float16  half2v;   // packed f16 (v_dot2)

#define GLDS(g, l) __builtin_amdgcn_global_load_lds( \
    (__attribute__((address_space(1))) void*)(g),    \
    (__attribute__((address_space(3))) void*)(l), 16, 0, 0)

__device__ __forceinline__ unsigned short f2bf_bits(float f) {
  __hip_bfloat16 h = __float2bfloat16(f);
  return *reinterpret_cast<unsigned short*>(&h);
}
__device__ __forceinline__ float bf_bits2f(unsigned short u) {
  unsigned int x = ((unsigned int)u) << 16;
  return __uint_as_float(x);
}
__device__ __forceinline__ float sigm(float x) {
  return __fdividef(1.0f, 1.0f + __expf(-x));
}
__device__ __forceinline__ float tanh_fast(float x) {
  return 1.0f - __fdividef(2.0f, __expf(2.0f * x) + 1.0f);
}

__device__ __forceinline__ unsigned int pack_f16x2(float a, float b) {
  half2v h; h.x = (_Float16)a; h.y = (_Float16)b;
  return __builtin_bit_cast(unsigned int, h);
}
__device__ __forceinline__ half2v u2h2(unsigned int u) {
  return __builtin_bit_cast(half2v, u);
}

#if __has_builtin(__builtin_amdgcn_fdot2)
__device__ __forceinline__ float fdot2(half2v a, half2v b, float c) {
  return __builtin_amdgcn_fdot2(a, b, c, false);   // v_dot2_f32_f16, fp32 acc
}
#else
__device__ __forceinline__ float fdot2(half2v a, half2v b, float c) {
  return fmaf((float)a.x, (float)b.x, fmaf((float)a.y, (float)b.y, c));
}
#endif

// Butterfly sum across a quad — pure VALU DPP (no DS pipe).
__device__ __forceinline__ float quad_bfly_add(float x) {
  float y = x + __int_as_float(
      __builtin_amdgcn_mov_dpp(__float_as_int(x), 0xB1, 0xF, 0xF, true));
  return y + __int_as_float(
      __builtin_amdgcn_mov_dpp(__float_as_int(y), 0x4E, 0xF, 0xF, true));
}

// LDS-only barrier: s_waitcnt lgkmcnt(0) + s_barrier, WITHOUT the vmcnt(0)
// drain __syncthreads() forces. The only cross-thread data through the
// per-step barrier is the LDS h ping-pong (covered by lgkmcnt). In-flight
// global ops (xg prefetch loads, y stores) have no cross-thread consumers
// and must NOT be drained per step — that drain was R1-R6's hidden
// ~1000 cyc/step serialization.
__device__ __forceinline__ void barrier_lds_only() {
  __asm__ __volatile__("s_waitcnt lgkmcnt(0)\n\ts_barrier" ::: "memory");
}

// xg element type templated: float (precise) if workspace allows, bf16 otherwise.
__device__ __forceinline__ void  store_xg(float* p, float v)  { *p = v; }
__device__ __forceinline__ void  store_xg(unsigned short* p, float v) { *p = f2bf_bits(v); }
__device__ __forceinline__ float load_xg(const float* p)  { return *p; }
__device__ __forceinline__ float load_xg(const unsigned short* p) { return bf_bits2f(*p); }

// ---------------------------------------------------------------------------
// Embedding gather: x0[b,t,:] = bf16(emb[X[b,t],:]).
__global__ void k_gather(const int* __restrict__ X, const float* __restrict__ emb,
                         unsigned short* __restrict__ x0) {
  int i = blockIdx.x * 256 + threadIdx.x;
  int row = i >> 5, c4 = i & 31;
  float4 v = ((const float4*)emb)[(size_t)X[row] * 32 + c4];
  ushort4 o;
  o.x = f2bf_bits(v.x); o.y = f2bf_bits(v.y); o.z = f2bf_bits(v.z); o.w = f2bf_bits(v.w);
  ((ushort4*)x0)[i] = o;
}

// Per-layer prep: w_ih -> bf16, bias_sum = b_ih + b_hh.
__global__ void k_prep(const float* __restrict__ w, const float* __restrict__ bi,
                       const float* __restrict__ bh, unsigned short* __restrict__ wb,
                       float* __restrict__ bias, int nw) {
  int i = blockIdx.x * blockDim.x + threadIdx.x;
  int stride = gridDim.x * blockDim.x;
  for (int k = i; k < nw; k += stride) wb[k] = f2bf_bits(w[k]);
  for (int k = i; k < 2 * G4; k += stride) bias[k] = bi[k] + bh[k];
}

// W_hh f16-pack into the scan's lane-coalesced layout (unchanged from R6).
__global__ void k_prep_whh(const float* __restrict__ Whh, unsigned int* __restrict__ wf) {
  int i = blockIdx.x * 256 + threadIdx.x;          // [0, 65536)
  int dir = i >> 15;
  int t2  = i & 0x7FFF;
  int jq  = t2 >> 11;
  int t3  = t2 & 0x7FF;
  int ts  = t3 >> 2;
  int q   = t3 & 3;
  int d   = jq * 4 + q;
  int g   = d >> 4;
  int jj  = d & 15;
  int lane = ts & 63, wave = ts >> 6;
  int p = lane & 3, ul = lane >> 2;
  int u = wave * 16 + ul;
  int k = 32 * p + 2 * jj;
  const float* wr = Whh + ((size_t)dir * G4 + g * H_ + u) * H_ + k;
  wf[i] = pack_f16x2(wr[0], wr[1]);
}

// ---------------------------------------------------------------------------
// Input-projection GEMM (NT) — unchanged from R1 (m97-style, verified).
template <typename XG_T>
__global__ __launch_bounds__(256, 2) void k_gemm(
    const unsigned short* __restrict__ A,   // [M_, K] bf16 row-major
    const unsigned short* __restrict__ W,   // [2][G4][K] bf16 row-major
    const float* __restrict__ bias,         // [2][G4]
    XG_T* __restrict__ xg,                  // [2][M_][G4]
    int K) {
  __shared__ unsigned short sA[128 * 32];
  __shared__ unsigned short sB[128 * 32];
  const int tid  = threadIdx.x;
  const int lane = tid & 63;
  const int wave = tid >> 6;
  const int mt = blockIdx.x, nt = blockIdx.y, dir = blockIdx.z;
  const size_t Arow0 = (size_t)mt * 128;
  const int    Ncol0 = nt * 128;
  const unsigned short* Wd = W + (size_t)dir * G4 * K;

  const int srow = tid >> 2;
  const int qlog = (tid & 3) ^ ((tid >> 4) & 3);
  auto ldsA0 = (__attribute__((address_space(3))) void*)(sA + wave * 512);
  auto ldsA1 = (__attribute__((address_space(3))) void*)(sA + 2048 + wave * 512);
  auto ldsB0 = (__attribute__((address_space(3))) void*)(sB + wave * 512);
  auto ldsB1 = (__attribute__((address_space(3))) void*)(sB + 2048 + wave * 512);

  floatx4 acc[4][4];
#pragma unroll
  for (int i = 0; i < 4; ++i)
#pragma unroll
    for (int j = 0; j < 4; ++j) acc[i][j] = (floatx4)0.0f;

  const int wrow = (wave >> 1) * 64, wcol = (wave & 1) * 64;
  const int frow = lane & 15;
  const int fq   = lane >> 4;

  for (int kt = 0; kt < K; kt += 32) {
    const unsigned short* gA0 = A  + (Arow0 + srow) * (size_t)K + kt + qlog * 8;
    const unsigned short* gB0 = Wd + (size_t)(Ncol0 + srow) * K + kt + qlog * 8;
    GLDS(gA0, ldsA0);
    GLDS(gA0 + (size_t)64 * K, ldsA1);
    GLDS(gB0, ldsB0);
    GLDS(gB0 + (size_t)64 * K, ldsB1);
    __syncthreads();

    short8 af[4], bf[4];
#pragma unroll
    for (int i = 0; i < 4; ++i) {
      int r  = wrow + 16 * i + frow;
      int rn = wcol + 16 * i + frow;
      af[i] = *(const short8*)(sA + r  * 32 + ((fq ^ ((r  >> 2) & 3)) * 8));
      bf[i] = *(const short8*)(sB + rn * 32 + ((fq ^ ((rn >> 2) & 3)) * 8));
    }
#pragma unroll
    for (int i = 0; i < 4; ++i)
#pragma unroll
      for (int j = 0; j < 4; ++j)
        acc[i][j] = __builtin_amdgcn_mfma_f32_16x16x32_bf16(af[i], bf[j], acc[i][j], 0, 0, 0);
    __syncthreads();
  }

  const int r0 = (lane >> 4) * 4;
  const int cc = lane & 15;
  XG_T* xgd = xg + (size_t)dir * M_ * G4;
#pragma unroll
  for (int j = 0; j < 4; ++j) {
    int gcol = Ncol0 + wcol + 16 * j + cc;
    float bs = bias[dir * G4 + gcol];
#pragma unroll
    for (int i = 0; i < 4; ++i) {
      size_t rowb = Arow0 + wrow + 16 * i + r0;
#pragma unroll
      for (int r = 0; r < 4; ++r)
        store_xg(&xgd[(rowb + r) * G4 + gcol], acc[i][j][r] + bs);
    }
  }
}

// ---------------------------------------------------------------------------
// Recurrent scan (R6 math, R7 memory schedule). One block per (dir,b),
// 512 threads = 8 waves; lane = (ul=lane>>2, p=lane&3); W_hh f16-packed,
// 64 dwords/lane VGPR-resident (R6-verified). NEW in R7:
//  - t-loop unrolled x2 with TWO pending xg registers consumed DIRECTLY
//    (no xv=xn copy): each load's first data-use is ~2 sub-steps (~1000 cyc)
//    after issue -> HBM latency off the critical path.
//  - per-step barrier is lgkmcnt-only (no vmcnt drain of prefetch/stores).
//  - running pointers for xg and y (no per-step 64-bit address mul).
template <typename XG_T>
__global__ __attribute__((amdgpu_flat_work_group_size(512, 512),
                          amdgpu_waves_per_eu(2, 2))) void k_scan(
    const unsigned int* __restrict__ wf,  // [2][16][512][4] packed f16 pairs
    const float* __restrict__ hx0,        // [2][B_][H_] (layer base)
    const float* __restrict__ cx0,
    const XG_T* __restrict__ xg,          // [2][M_][G4]
    unsigned short* __restrict__ y)       // [B_][T_][2*H_] bf16
{
  const int b   = blockIdx.x & 63;
  const int dir = blockIdx.x >> 6;
  const int tid = threadIdx.x;
  const int lane = tid & 63;
  const int wave = tid >> 6;
  const int p  = lane & 3;        // k-slice (32 k each)
  const int ul = lane >> 2;       // unit within wave
  const int u  = wave * 16 + ul;

  __shared__ __align__(16) unsigned short h16[2][128];

  // Weights: 16 coalesced uint4 loads; d = g*16+jj -> wv[d>>2][d&3] holds the
  // f16 pair (k=32p+2jj, k+1) of gate g for unit u. VGPR-resident (R6: VGPR 88).
  uint4 wv[16];
  const uint4* wfv = (const uint4*)wf;
#pragma unroll
  for (int i = 0; i < 16; ++i) wv[i] = wfv[(dir * 16 + i) * 512 + tid];

  float c = cx0[(size_t)dir * B_ * H_ + b * H_ + u];   // replicated over quad
  if (p == 0) {
    float h0 = hx0[(size_t)dir * B_ * H_ + b * H_ + u];
    h16[0][u] = (unsigned short)(pack_f16x2(h0, 0.0f) & 0xFFFF);
  }

  // xg running pointers (strength-reduced; dir handled once)
  const XG_T* xgb = xg + ((size_t)dir * M_ + (size_t)b * T_) * G4;
  const intptr_t xstep = dir ? -(intptr_t)G4 : (intptr_t)G4;
  const XG_T* xrow0 = xgb + (dir ? (size_t)(T_ - 1) * G4 : 0) + p * H_ + u;
  float xp0 = load_xg(xrow0);             // pending for sub-step t (even)
  float xp1 = load_xg(xrow0 + xstep);     // pending for sub-step t+1 (odd)
  const XG_T* xld = xrow0 + 2 * xstep;    // next load target: step t+2

  unsigned short* yp = y + ((size_t)b * T_ + (dir ? T_ - 1 : 0)) * (2 * H_)
                         + dir * H_ + u;
  const intptr_t ystep = dir ? -(intptr_t)(2 * H_) : (intptr_t)(2 * H_);

  __syncthreads();   // init h visible (full drain fine, once)

  // dot phase: reads h16[par], folds xv for gate p, returns 4 gate pre-sums
  auto dots = [&](int par, float xv, float& g0, float& g1, float& g2, float& g3) {
    const uint4* hv4 = (const uint4*)&h16[par][0];
    uint4 h0v = hv4[4 * p + 0], h1v = hv4[4 * p + 1];
    uint4 h2v = hv4[4 * p + 2], h3v = hv4[4 * p + 3];
    half2v hh[16] = {
      u2h2(h0v.x), u2h2(h0v.y), u2h2(h0v.z), u2h2(h0v.w),
      u2h2(h1v.x), u2h2(h1v.y), u2h2(h1v.z), u2h2(h1v.w),
      u2h2(h2v.x), u2h2(h2v.y), u2h2(h2v.z), u2h2(h2v.w),
      u2h2(h3v.x), u2h2(h3v.y), u2h2(h3v.z), u2h2(h3v.w)};
    g0 = 0; g1 = 0; g2 = 0; g3 = 0;
#pragma unroll
    for (int j = 0; j < 16; ++j) {
      g0 = fdot2(u2h2(((const unsigned int*)&wv[(0 * 16 + j) >> 2])[(0 * 16 + j) & 3]), hh[j], g0);
      g1 = fdot2(u2h2(((const unsigned int*)&wv[(1 * 16 + j) >> 2])[(1 * 16 + j) & 3]), hh[j], g1);
      g2 = fdot2(u2h2(((const unsigned int*)&wv[(2 * 16 + j) >> 2])[(2 * 16 + j) & 3]), hh[j], g2);
      g3 = fdot2(u2h2(((const unsigned int*)&wv[(3 * 16 + j) >> 2])[(3 * 16 + j) & 3]), hh[j], g3);
    }
    g0 += (p == 0) ? xv : 0.0f;
    g1 += (p == 1) ? xv : 0.0f;
    g2 += (p == 2) ? xv : 0.0f;
    g3 += (p == 3) ? xv : 0.0f;
  };

  // reduce + nonlin + state update + h/y writes + LDS-only barrier
  auto finish = [&](int par, float g0, float g1, float g2, float g3) {
    g0 = quad_bfly_add(g0);
    g1 = quad_bfly_add(g1);
    g2 = quad_bfly_add(g2);
    g3 = quad_bfly_add(g3);
    float iv = sigm(g0), fv = sigm(g1), gv = tanh_fast(g2), ov = sigm(g3);
    c = fmaf(fv, c, iv * gv);
    float h = ov * tanh_fast(c);
    if (p == 0) {
      h16[par ^ 1][u] = (unsigned short)(pack_f16x2(h, 0.0f) & 0xFFFF);
      *yp = f2bf_bits(h);
    }
    yp += ystep;
    barrier_lds_only();
  };

  for (int t = 0; t < T_; t += 2) {
    float a0, a1, a2, a3;
    // ---- even sub-step: consume xp0 (loaded 2 sub-steps ago) ----
    dots(0, xp0, a0, a1, a2, a3);
    xp0 = (t + 2 < T_) ? load_xg(xld) : 0.0f;   // direct overwrite after last
    xld += xstep;                               // use; next use 2 steps away
    finish(0, a0, a1, a2, a3);
    // ---- odd sub-step: consume xp1 ----
    dots(1, xp1, a0, a1, a2, a3);
    xp1 = (t + 3 < T_) ? load_xg(xld) : 0.0f;
    xld += xstep;
    finish(1, a0, a1, a2, a3);
  }
}

// ---------------------------------------------------------------------------
// Head: out[b] = y2[b, T-1, :] . lin_w + lin_b
__global__ void k_head(const unsigned short* __restrict__ y2, const float* __restrict__ lw,
                       const float* __restrict__ lb, float* __restrict__ out) {
  int b = blockIdx.x, l = threadIdx.x;
  const unsigned short* row = y2 + ((size_t)b * T_ + (T_ - 1)) * (2 * H_);
  float s = 0;
#pragma unroll
  for (int k = 0; k < 4; ++k) s += bf_bits2f(row[l + 64 * k]) * lw[l + 64 * k];
#pragma unroll
  for (int off = 32; off > 0; off >>= 1) s += __shfl_down(s, off);
  if (l == 0) out[b] = s + lb[0];
}

// ---------------------------------------------------------------------------
template <typename XG_T>
static inline void run_layers(const unsigned int* const* wfs,
                              const unsigned short* x0,
                              unsigned short* y0, unsigned short* y1, unsigned short* y2,
                              const unsigned short* wb0, const unsigned short* wb1,
                              const unsigned short* wb2,
                              const float* bias0, const float* bias1, const float* bias2,
                              const float* hx, const float* cx,
                              XG_T* xg, hipStream_t stream) {
  dim3 gg(M_ / 128, G4 / 128, 2);
  k_gemm<XG_T><<<gg, 256, 0, stream>>>(x0, wb0, bias0, xg, EMB_);
  k_scan<XG_T><<<128, 512, 0, stream>>>(wfs[0], hx, cx, xg, y0);
  k_gemm<XG_T><<<gg, 256, 0, stream>>>(y0, wb1, bias1, xg, 2 * H_);
  k_scan<XG_T><<<128, 512, 0, stream>>>(wfs[1], hx + 2 * B_ * H_, cx + 2 * B_ * H_, xg, y1);
  k_gemm<XG_T><<<gg, 256, 0, stream>>>(y1, wb2, bias2, xg, 2 * H_);
  k_scan<XG_T><<<128, 512, 0, stream>>>(wfs[2], hx + 4 * B_ * H_, cx + 4 * B_ * H_, xg, y2);
}

extern "C" void kernel_launch(void* const* d_in, const int* in_sizes, int n_in,
                              void* d_out, int out_size, void* d_ws, size_t ws_size,
                              hipStream_t stream) {
  const int*   X   = (const int*)d_in[0];
  const float* emb = (const float*)d_in[1];
  const float* hx  = (const float*)d_in[2];
  const float* cx  = (const float*)d_in[3];
  const float* lw  = (const float*)d_in[4];
  const float* lb  = (const float*)d_in[5];
  const float* w_ih[3] = {(const float*)d_in[6],  (const float*)d_in[10], (const float*)d_in[14]};
  const float* w_hh[3] = {(const float*)d_in[7],  (const float*)d_in[11], (const float*)d_in[15]};
  const float* b_ih[3] = {(const float*)d_in[8],  (const float*)d_in[12], (const float*)d_in[16]};
  const float* b_hh[3] = {(const float*)d_in[9],  (const float*)d_in[13], (const float*)d_in[17]};
  float* out = (float*)d_out;

  char* ws = (char*)d_ws;
  size_t off = 0;
  auto carve = [&](size_t bytes) {
    char* p = ws + off;
    off = (off + bytes + 255) & ~(size_t)255;
    return p;
  };
  unsigned short* x0  = (unsigned short*)carve((size_t)M_ * EMB_ * 2);
  unsigned short* y0  = (unsigned short*)carve((size_t)M_ * 2 * H_ * 2);
  unsigned short* y1  = (unsigned short*)carve((size_t)M_ * 2 * H_ * 2);
  unsigned short* y2  = (unsigned short*)carve((size_t)M_ * 2 * H_ * 2);
  unsigned short* wb0 = (unsigned short*)carve((size_t)2 * G4 * EMB_ * 2);
  unsigned short* wb1 = (unsigned short*)carve((size_t)2 * G4 * 2 * H_ * 2);
  unsigned short* wb2 = (unsigned short*)carve((size_t)2 * G4 * 2 * H_ * 2);
  float* bias0 = (float*)carve(2 * G4 * 4);
  float* bias1 = (float*)carve(2 * G4 * 4);
  float* bias2 = (float*)carve(2 * G4 * 4);
  unsigned int* wf0 = (unsigned int*)carve((size_t)65536 * 4);
  unsigned int* wf1 = (unsigned int*)carve((size_t)65536 * 4);
  unsigned int* wf2 = (unsigned int*)carve((size_t)65536 * 4);
  const size_t xg_f32_bytes = (size_t)2 * M_ * G4 * 4;
  const bool use_f32 = (off + xg_f32_bytes) <= ws_size;
  void* xg = carve(use_f32 ? xg_f32_bytes : xg_f32_bytes / 2);

  k_prep<<<256, 256, 0, stream>>>(w_ih[0], b_ih[0], b_hh[0], wb0, bias0, 2 * G4 * EMB_);
  k_prep<<<256, 256, 0, stream>>>(w_ih[1], b_ih[1], b_hh[1], wb1, bias1, 2 * G4 * 2 * H_);
  k_prep<<<256, 256, 0, stream>>>(w_ih[2], b_ih[2], b_hh[2], wb2, bias2, 2 * G4 * 2 * H_);
  k_prep_whh<<<256, 256, 0, stream>>>(w_hh[0], wf0);
  k_prep_whh<<<256, 256, 0, stream>>>(w_hh[1], wf1);
  k_prep_whh<<<256, 256, 0, stream>>>(w_hh[2], wf2);
  k_gather<<<(M_ * 32) / 256, 256, 0, stream>>>(X, emb, x0);

  const unsigned int* wfs[3] = {wf0, wf1, wf2};
  if (use_f32)
    run_layers<float>(wfs, x0, y0, y1, y2, wb0, wb1, wb2, bias0, bias1, bias2,
                      hx, cx, (float*)xg, stream);
  else
    run_layers<unsigned short>(wfs, x0, y0, y1, y2, wb0, wb1, wb2, bias0, bias1, bias2,
                               hx, cx, (unsigned short*)xg, stream);

  k_head<<<64, 64, 0, stream>>>(y2, lw, lb, out);
}